// Round 7
// baseline (308.111 us; speedup 1.0000x reference)
//
#include <hip/hip_runtime.h>
#include <math.h>

typedef __bf16 bf16x8 __attribute__((ext_vector_type(8)));
typedef float f32x4 __attribute__((ext_vector_type(4)));

__device__ __forceinline__ bf16x8 to_bf16x8(float4 a, float4 b) {
    bf16x8 r;
    r[0] = (__bf16)a.x; r[1] = (__bf16)a.y; r[2] = (__bf16)a.z; r[3] = (__bf16)a.w;
    r[4] = (__bf16)b.x; r[5] = (__bf16)b.y; r[6] = (__bf16)b.z; r[7] = (__bf16)b.w;
    return r;
}
#define MFMA16(A, B, C) __builtin_amdgcn_mfma_f32_16x16x32_bf16((A), (B), (C), 0, 0, 0)

__device__ __forceinline__ float rsum32(float v) {
    v += __shfl_xor(v, 1, 32); v += __shfl_xor(v, 2, 32);
    v += __shfl_xor(v, 4, 32); v += __shfl_xor(v, 8, 32);
    v += __shfl_xor(v, 16, 32);
    return v;
}
__device__ __forceinline__ float rmax32(float v) {
    v = fmaxf(v, __shfl_xor(v, 1, 32)); v = fmaxf(v, __shfl_xor(v, 2, 32));
    v = fmaxf(v, __shfl_xor(v, 4, 32)); v = fmaxf(v, __shfl_xor(v, 8, 32));
    v = fmaxf(v, __shfl_xor(v, 16, 32));
    return v;
}

// 32-wide matvec: OUT = sum_j EV[j]*SRC[j], 4-way split accumulators.
#define MATVEC32(SRC, EV, OUT)                                                 \
    {                                                                          \
        const float4* uv_ = (const float4*)(SRC);                              \
        float4 u0_ = uv_[0], u1_ = uv_[1], u2_ = uv_[2], u3_ = uv_[3];         \
        float4 u4_ = uv_[4], u5_ = uv_[5], u6_ = uv_[6], u7_ = uv_[7];         \
        float a0_ = EV[0]*u0_.x + EV[1]*u0_.y + EV[2]*u0_.z + EV[3]*u0_.w;     \
        float a1_ = EV[4]*u1_.x + EV[5]*u1_.y + EV[6]*u1_.z + EV[7]*u1_.w;     \
        float a2_ = EV[8]*u2_.x + EV[9]*u2_.y + EV[10]*u2_.z + EV[11]*u2_.w;   \
        float a3_ = EV[12]*u3_.x + EV[13]*u3_.y + EV[14]*u3_.z + EV[15]*u3_.w; \
        a0_ += EV[16]*u4_.x + EV[17]*u4_.y + EV[18]*u4_.z + EV[19]*u4_.w;      \
        a1_ += EV[20]*u5_.x + EV[21]*u5_.y + EV[22]*u5_.z + EV[23]*u5_.w;      \
        a2_ += EV[24]*u6_.x + EV[25]*u6_.y + EV[26]*u6_.z + EV[27]*u6_.w;      \
        a3_ += EV[28]*u7_.x + EV[29]*u7_.y + EV[30]*u7_.z + EV[31]*u7_.w;      \
        OUT = (a0_ + a1_) + (a2_ + a3_);                                       \
    }

// ---------------------------------------------------------------------------
// k_word: fused per-word pipeline, 128 threads (2 waves), 1 word/block.
// A: MFMA dots -> LDS.  B: gd = exp(dots - rowmax).
// C: alpha (wave0) || beta (wave1), UNNORMALIZED scaled recursions with a
//    register renorm every 8 steps (exact: p1/p2 are per-position scale-free;
//    beta boundary factors recorded in bscale[] and re-applied in phase D).
// D: p1 -> Pdiff; rank-1 S -> global atomics into dTacc (64 slices) + hist.
// ---------------------------------------------------------------------------
__global__ __launch_bounds__(128) void k_word(const float* __restrict__ data,
                                              const float* __restrict__ W,
                                              const float* __restrict__ Tm,
                                              const int* __restrict__ labels,
                                              float* __restrict__ Pdiff,
                                              float* __restrict__ dTacc) {
    __shared__ __align__(16) float gdb[2048];  // raw dots -> gd
    __shared__ __align__(16) float Unb[2048];  // alpha*gd (per-i arbitrary scale)
    __shared__ __align__(16) float Mb[2048];   // beta matvec chain
    __shared__ float wtmp[32];
    __shared__ float bscale[64];
    __shared__ int lab[64];

    const int n = blockIdx.x;
    const int tid = threadIdx.x;
    const int wv = tid >> 6;       // 0: alpha, 1: beta
    const int lane = tid & 63;
    const int k = tid & 31;
    const int hw = tid >> 5;       // half-wave id 0..3
    float* drow = Pdiff + (size_t)n * 2048;

    // ---- Phase A: MFMA dots into LDS ----
    {
        const int m16 = lane & 15;
        const int kb = lane >> 4;
        const size_t row0 = (size_t)n * 64 + wv * 32;
        const float* arow0 = data + (row0 + m16) * 512 + kb * 8;
        const float* arow1 = arow0 + 16 * 512;
        const float* brow0 = W + (size_t)m16 * 512 + kb * 8;
        const float* brow1 = brow0 + 16 * 512;

        f32x4 acc00 = {0.f, 0.f, 0.f, 0.f}, acc01 = {0.f, 0.f, 0.f, 0.f};
        f32x4 acc10 = {0.f, 0.f, 0.f, 0.f}, acc11 = {0.f, 0.f, 0.f, 0.f};

#pragma unroll 1   // full unroll spills (r3: 256 VGPR, 400 MB scratch)
        for (int kk = 0; kk < 16; ++kk) {
            const int off = kk * 32;
            float4 a0l = *(const float4*)(arow0 + off);
            float4 a0h = *(const float4*)(arow0 + off + 4);
            float4 a1l = *(const float4*)(arow1 + off);
            float4 a1h = *(const float4*)(arow1 + off + 4);
            float4 b0l = *(const float4*)(brow0 + off);
            float4 b0h = *(const float4*)(brow0 + off + 4);
            float4 b1l = *(const float4*)(brow1 + off);
            float4 b1h = *(const float4*)(brow1 + off + 4);
            bf16x8 a0 = to_bf16x8(a0l, a0h), a1 = to_bf16x8(a1l, a1h);
            bf16x8 b0 = to_bf16x8(b0l, b0h), b1 = to_bf16x8(b1l, b1h);
            acc00 = MFMA16(a0, b0, acc00);
            acc01 = MFMA16(a0, b1, acc01);
            acc10 = MFMA16(a1, b0, acc10);
            acc11 = MFMA16(a1, b1, acc11);
        }
        const int ib = wv * 32 + kb * 4;
#pragma unroll
        for (int r = 0; r < 4; ++r) {
            gdb[(ib + r) * 32 + m16]           = acc00[r];
            gdb[(ib + r) * 32 + 16 + m16]      = acc01[r];
            gdb[(ib + 16 + r) * 32 + m16]      = acc10[r];
            gdb[(ib + 16 + r) * 32 + 16 + m16] = acc11[r];
        }
    }
    if (tid < 64) { lab[tid] = labels[n * 64 + tid]; bscale[tid] = 1.f; }
    __syncthreads();

    // ---- Phase B: gd[i][k] = exp(dots - rowmax) ----
#pragma unroll
    for (int ii = 0; ii < 16; ++ii) {
        int i = hw * 16 + ii;
        float d = gdb[i * 32 + k];
        float mx = rmax32(d);
        gdb[i * 32 + k] = __expf(d - mx);
    }
    __syncthreads();

    // ---- Phase C: alpha || beta (deferred normalization) ----
    if (wv == 0) {
        float Ecol[32];
#pragma unroll
        for (int j = 0; j < 32; ++j) Ecol[j] = __expf(Tm[j * 32 + k]);
        float Areg = 1.f;
        float gdc = gdb[k];
#pragma unroll 1
        for (int g = 0; g < 8; ++g) {
#pragma unroll
            for (int ii = 0; ii < 8; ++ii) {
                const int i = g * 8 + ii;
                float t = Areg * gdc;
                Unb[i * 32 + k] = t;
                if (i < 63) gdc = gdb[(i + 1) * 32 + k];
                asm volatile("s_waitcnt lgkmcnt(0)" ::: "memory");
                if (i < 63) {
                    float anew;
                    MATVEC32(&Unb[i * 32], Ecol, anew);
                    Areg = anew;
                }
            }
            if (g < 7) Areg *= __builtin_amdgcn_rcpf(rsum32(Areg));
        }
    } else {
        float Erow[32];
#pragma unroll
        for (int j = 0; j < 32; ++j) Erow[j] = __expf(Tm[k * 32 + j]);
        float Mreg = 1.f;
        Mb[63 * 32 + k] = 1.f;
        float gdc = gdb[63 * 32 + k];
#pragma unroll 1
        for (int g = 0; g < 8; ++g) {
#pragma unroll
            for (int ii = 0; ii < 8; ++ii) {
                const int s = g * 8 + ii;
                if (s < 63) {
                    const int i = 63 - s;
                    float ww = gdc * Mreg;
                    wtmp[k] = ww;
                    gdc = gdb[(i - 1) * 32 + k];
                    asm volatile("s_waitcnt lgkmcnt(0)" ::: "memory");
                    float m2;
                    MATVEC32(wtmp, Erow, m2);
                    Mb[(i - 1) * 32 + k] = m2;
                    Mreg = m2;
                }
            }
            if (g < 7) {
                float rc = __builtin_amdgcn_rcpf(rsum32(Mreg));
                Mreg *= rc;
                // next write is Mb[54-8g] = rc * E(G∘Mb[55-8g]) -> record rc
                if (lane == 0) bscale[54 - 8 * g] = rc;
            }
        }
    }
    __syncthreads();

    // ---- Phase D: p-phase, 4 half-waves x 16 positions ----
    float EcolD[32];
#pragma unroll
    for (int j = 0; j < 32; ++j) EcolD[j] = __expf(Tm[j * 32 + k]);
    float Scol[32];
#pragma unroll
    for (int j = 0; j < 32; ++j) Scol[j] = 0.f;
    const int i0 = hw * 16;
    for (int ii = 0; ii < 16; ++ii) {
        const int i = i0 + ii;
        float un = Unb[i * 32 + k];
        float mm = Mb[i * 32 + k];
        float t = un * mm;
        float Z = rsum32(t);
        float rZ = __builtin_amdgcn_rcpf(Z);
        float pd = ((lab[i] == k) ? 1.f : 0.f) - t * rZ;
        drow[i * 32 + k] = pd;
        if (i < 63) {
            float f = gdb[(i + 1) * 32 + k] * Mb[(i + 1) * 32 + k] * rZ * bscale[i];
            const float4* uv = (const float4*)(&Unb[i * 32]);
#pragma unroll
            for (int j8 = 0; j8 < 8; ++j8) {
                float4 u = uv[j8];
                Scol[j8 * 4 + 0] += u.x * f; Scol[j8 * 4 + 1] += u.y * f;
                Scol[j8 * 4 + 2] += u.z * f; Scol[j8 * 4 + 3] += u.w * f;
            }
        }
    }
    float* ta = dTacc + (size_t)(n & 63) * 1024;
#pragma unroll
    for (int j = 0; j < 32; ++j) atomicAdd(&ta[j * 32 + k], -EcolD[j] * Scol[j]);
    if (tid < 63) atomicAdd(&ta[lab[tid] * 32 + lab[tid + 1]], 1.0f);
}

// ---------------------------------------------------------------------------
// K3: dw partials = Pdiff^T @ data. grid = 256 word-groups x 4 d-quarters.
// ---------------------------------------------------------------------------
__global__ __launch_bounds__(256) void k_dw(const float* __restrict__ data,
                                            const float* __restrict__ Pd,
                                            float* __restrict__ dwp) {
    const int g = blockIdx.x >> 2;
    const int q = blockIdx.x & 3;
    const int tid = threadIdx.x;
    const int kg = __builtin_amdgcn_readfirstlane(tid >> 6);
    const int lane = tid & 63;
    const int k0 = kg << 3;
    const int d0 = q * 128 + lane * 2;

    float2 acc[8];
#pragma unroll
    for (int i = 0; i < 8; ++i) acc[i] = make_float2(0.f, 0.f);

    const size_t rbase = (size_t)g * 512;
    const float* dptr = data + rbase * 512 + d0;
    const float4* pptr = (const float4*)(Pd + rbase * 32) + kg * 2;

#define FMA8_2(PA, PB, DV)                                                     \
    acc[0].x += (PA).x * (DV).x; acc[0].y += (PA).x * (DV).y;                  \
    acc[1].x += (PA).y * (DV).x; acc[1].y += (PA).y * (DV).y;                  \
    acc[2].x += (PA).z * (DV).x; acc[2].y += (PA).z * (DV).y;                  \
    acc[3].x += (PA).w * (DV).x; acc[3].y += (PA).w * (DV).y;                  \
    acc[4].x += (PB).x * (DV).x; acc[4].y += (PB).x * (DV).y;                  \
    acc[5].x += (PB).y * (DV).x; acc[5].y += (PB).y * (DV).y;                  \
    acc[6].x += (PB).z * (DV).x; acc[6].y += (PB).z * (DV).y;                  \
    acc[7].x += (PB).w * (DV).x; acc[7].y += (PB).w * (DV).y;

    for (int r = 0; r < 512; r += 4) {
        float2 dv0 = *(const float2*)(dptr + (size_t)(r + 0) * 512);
        float2 dv1 = *(const float2*)(dptr + (size_t)(r + 1) * 512);
        float2 dv2 = *(const float2*)(dptr + (size_t)(r + 2) * 512);
        float2 dv3 = *(const float2*)(dptr + (size_t)(r + 3) * 512);
        float4 pa0 = pptr[(r + 0) * 8], pb0 = pptr[(r + 0) * 8 + 1];
        float4 pa1 = pptr[(r + 1) * 8], pb1 = pptr[(r + 1) * 8 + 1];
        float4 pa2 = pptr[(r + 2) * 8], pb2 = pptr[(r + 2) * 8 + 1];
        float4 pa3 = pptr[(r + 3) * 8], pb3 = pptr[(r + 3) * 8 + 1];
        FMA8_2(pa0, pb0, dv0)
        FMA8_2(pa1, pb1, dv1)
        FMA8_2(pa2, pb2, dv2)
        FMA8_2(pa3, pb3, dv3)
    }
#undef FMA8_2

    float* op = dwp + (size_t)g * 16384;
#pragma unroll
    for (int kk = 0; kk < 8; ++kk)
        *(float2*)(op + (k0 + kk) * 512 + d0) = acc[kk];
}

// ---------------------------------------------------------------------------
// K4: blocks 0..255: reduce dw partials; block 256: reduce dTacc (64 slices).
// ---------------------------------------------------------------------------
__global__ __launch_bounds__(256) void k_final(const float* __restrict__ dwp,
                                               const float* __restrict__ dTacc,
                                               float* __restrict__ out) {
    __shared__ float red[256];
    const int b = blockIdx.x, t = threadIdx.x;
    const float inv = 1.0f / 2048.0f;
    if (b < 256) {
        const int q = t >> 6, ol = t & 63;
        const int oi = b * 64 + ol;
        float s = 0.f;
#pragma unroll 4
        for (int j = 0; j < 64; ++j) s += dwp[(size_t)(q * 64 + j) * 16384 + oi];
        red[t] = s;
        __syncthreads();
        if (t < 64) out[b * 64 + t] = (red[t] + red[t + 64] + red[t + 128] + red[t + 192]) * inv;
    } else {
        const int t4 = t * 4;
        float s0 = 0.f, s1 = 0.f, s2 = 0.f, s3 = 0.f;
#pragma unroll 8
        for (int sl = 0; sl < 64; ++sl) {
            const float4 v = *(const float4*)(dTacc + sl * 1024 + t4);
            s0 += v.x; s1 += v.y; s2 += v.z; s3 += v.w;
        }
        float4 r = make_float4(s0 * inv, s1 * inv, s2 * inv, s3 * inv);
        *(float4*)(out + 16384 + t4) = r;
    }
}

// ---------------------------------------------------------------------------
// ws layout (floats): [0,4194304) Pdiff | [4194304,4259840) dTacc (64x1024)
//                     [6291456,10485760) dw partials
// ---------------------------------------------------------------------------
extern "C" void kernel_launch(void* const* d_in, const int* in_sizes, int n_in,
                              void* d_out, int out_size, void* d_ws, size_t ws_size,
                              hipStream_t stream) {
    const float* W = (const float*)d_in[0];
    const float* Tm = (const float*)d_in[1];
    const float* data = (const float*)d_in[2];
    const int* labels = (const int*)d_in[3];
    float* out = (float*)d_out;
    float* ws = (float*)d_ws;

    float* Pdiff = ws;                 // 2048*64*32
    float* dTacc = ws + 4194304;       // 64*1024
    float* dwpart = ws + 6291456;      // 256*16384

    hipMemsetAsync(dTacc, 0, 64 * 1024 * sizeof(float), stream);
    hipLaunchKernelGGL(k_word, dim3(2048), dim3(128), 0, stream,
                       data, W, Tm, labels, Pdiff, dTacc);
    hipLaunchKernelGGL(k_dw, dim3(1024), dim3(256), 0, stream, data, Pdiff, dwpart);
    hipLaunchKernelGGL(k_final, dim3(257), dim3(256), 0, stream, dwpart, dTacc, out);
}